// Round 4
// baseline (11638.020 us; speedup 1.0000x reference)
//
#include <hip/hip_runtime.h>

// DustRiskFormer: B=8 T=48 N=512 F=16 S=12 H=128 NH=8 HZ=6 NC=3
// Device buffers: ALL float tensors are f32 (reference dtype; round-3 NaN proved
// the bf16 assumption wrong), adj int32.
// Outputs (f32, concat flat): reg[8,512,6] risk[8,512,6,3] warn[8,512,6]
//                             t_attn[4096,48,48] alpha[8,512,512]

#define B_ 8
#define T_ 48
#define N_ 512
#define F_ 16
#define S_ 12
#define H_ 128
#define NH_ 8
#define HD_ 16

// dot of 128 f32 (16B-aligned LDS) with 128 f32 weights (global)
__device__ __forceinline__ float dot128(const float* __restrict__ a,
                                        const float* __restrict__ w) {
  float s = 0.f;
  #pragma unroll 8
  for (int c = 0; c < 32; ++c) {
    float4 av = *(const float4*)(a + 4 * c);
    float4 wv = *(const float4*)(w + 4 * c);
    s += av.x * wv.x + av.y * wv.y + av.z * wv.z + av.w * wv.w;
  }
  return s;
}
__device__ __forceinline__ float dot256(const float* __restrict__ a,
                                        const float* __restrict__ w) {
  float s = 0.f;
  #pragma unroll 8
  for (int c = 0; c < 64; ++c) {
    float4 av = *(const float4*)(a + 4 * c);
    float4 wv = *(const float4*)(w + 4 * c);
    s += av.x * wv.x + av.y * wv.y + av.z * wv.z + av.w * wv.w;
  }
  return s;
}

struct AttnBufs {
  float qk[2][T_][H_];      // 48KB (q,k f32)
  float v[T_][H_];          // 24KB
  float tatt[T_][T_];       // 9KB
};
struct alignas(16) SmemA {
  float h[T_][H_];          // 24KB  hidden state (residual-carrying)
  float attn[T_][H_];       // 24KB  attention output
  float xs[T_][F_];         // 3KB
  union { AttnBufs a; float g[T_][2 * H_]; } u;  // max 81KB
};                          // total ~132KB -> 1 block/CU, 8 waves

__global__ __launch_bounds__(512, 1)
void k_seq(const float* __restrict__ x,
           const float* __restrict__ pw,  const float* __restrict__ pb,
           const float* __restrict__ in_w, const float* __restrict__ in_b,
           const float* __restrict__ ow,  const float* __restrict__ ob,
           const float* __restrict__ l1g, const float* __restrict__ l1b,
           const float* __restrict__ w1,  const float* __restrict__ b1,
           const float* __restrict__ w2,  const float* __restrict__ b2,
           const float* __restrict__ l2g, const float* __restrict__ l2b,
           float* __restrict__ out_tatt, float* __restrict__ t_repr)
{
  __shared__ SmemA sm;
  const int seq = blockIdx.x;
  const int b = seq >> 9, n = seq & (N_ - 1);
  const int tid = threadIdx.x;

  // load x[b, :, n, :]  (48x16) and zero tatt
  for (int i = tid; i < T_ * F_; i += 512) {
    int t = i >> 4, f = i & 15;
    sm.xs[t][f] = x[((size_t)(b * T_ + t) * N_ + n) * F_ + f];
  }
  for (int i = tid; i < T_ * T_; i += 512) (&sm.u.a.tatt[0][0])[i] = 0.f;
  __syncthreads();

  // h = xs @ proj_w^T + proj_b   (48x128)
  for (int i = tid; i < T_ * H_; i += 512) {
    int t = i >> 7, hh = i & 127;
    float s = pb[hh];
    const float* wr = pw + hh * F_;
    #pragma unroll
    for (int f = 0; f < F_; ++f) s += sm.xs[t][f] * wr[f];
    sm.h[t][hh] = s;
  }
  __syncthreads();

  // qkv = h @ in_w^T + in_b   (48x384)
  for (int i = tid; i < T_ * 3 * H_; i += 512) {
    int t = i / (3 * H_), o = i % (3 * H_);
    float s = in_b[o] + dot128(sm.h[t], in_w + o * H_);
    int j = o >> 7, hh = o & 127;
    if (j == 2) sm.u.a.v[t][hh] = s;
    else        sm.u.a.qk[j][t][hh] = s;
  }
  __syncthreads();

  // attention: wave w = head w; lane r < 48 owns query-row r; scores in registers
  {
    const int w = tid >> 6, lane = tid & 63;
    if (lane < T_) {
      const int r = lane;
      float qv[HD_];
      #pragma unroll
      for (int d = 0; d < HD_; ++d) qv[d] = sm.u.a.qk[0][r][w * HD_ + d] * 0.25f;
      float sc[T_];
      float m = -1e30f;
      #pragma unroll
      for (int k = 0; k < T_; ++k) {
        float s = 0.f;
        #pragma unroll
        for (int d = 0; d < HD_; ++d) s += qv[d] * sm.u.a.qk[1][k][w * HD_ + d];
        sc[k] = s; m = fmaxf(m, s);
      }
      float sum = 0.f;
      #pragma unroll
      for (int k = 0; k < T_; ++k) { float p = __expf(sc[k] - m); sc[k] = p; sum += p; }
      float inv = 1.f / sum;
      #pragma unroll
      for (int k = 0; k < T_; ++k) {
        sc[k] *= inv;
        atomicAdd(&sm.u.a.tatt[r][k], sc[k] * 0.125f);   // mean over 8 heads
      }
      #pragma unroll
      for (int d = 0; d < HD_; ++d) {
        float acc = 0.f;
        #pragma unroll
        for (int k = 0; k < T_; ++k) acc += sc[k] * sm.u.a.v[k][w * HD_ + d];
        sm.attn[r][w * HD_ + d] = acc;
      }
    }
  }
  __syncthreads();

  // write t_attn; out-projection + residual into h
  for (int i = tid; i < T_ * T_; i += 512)
    out_tatt[(size_t)seq * T_ * T_ + i] = (&sm.u.a.tatt[0][0])[i];
  for (int i = tid; i < T_ * H_; i += 512) {
    int t = i >> 7, hh = i & 127;
    float s = ob[hh] + dot128(sm.attn[t], ow + hh * H_);
    sm.h[t][hh] += s;
  }
  __syncthreads();

  // LN1 (wave per row; lane covers elems lane, lane+64)
  {
    const int w = tid >> 6, lane = tid & 63;
    for (int t = w; t < T_; t += 8) {
      float v0 = sm.h[t][lane], v1 = sm.h[t][lane + 64];
      float s = v0 + v1;
      #pragma unroll
      for (int off = 32; off; off >>= 1) s += __shfl_xor(s, off, 64);
      float mean = s * (1.f / H_);
      float d0 = v0 - mean, d1 = v1 - mean;
      float q = d0 * d0 + d1 * d1;
      #pragma unroll
      for (int off = 32; off; off >>= 1) q += __shfl_xor(q, off, 64);
      float rstd = rsqrtf(q * (1.f / H_) + 1e-5f);
      sm.h[t][lane]      = d0 * rstd * l1g[lane]      + l1b[lane];
      sm.h[t][lane + 64] = d1 * rstd * l1g[lane + 64] + l1b[lane + 64];
    }
  }
  __syncthreads();

  // FFN: g = gelu(h @ w1^T + b1)  (48x256, overlays attn bufs)
  for (int i = tid; i < T_ * 2 * H_; i += 512) {
    int t = i >> 8, o = i & 255;
    float s = b1[o] + dot128(sm.h[t], w1 + o * H_);
    sm.u.g[t][o] = 0.5f * s * (1.f + erff(s * 0.70710678118f));
  }
  __syncthreads();
  for (int i = tid; i < T_ * H_; i += 512) {
    int t = i >> 7, hh = i & 127;
    float s = b2[hh] + dot256(sm.u.g[t], w2 + hh * 2 * H_);
    sm.h[t][hh] += s;
  }
  __syncthreads();

  // LN2
  {
    const int w = tid >> 6, lane = tid & 63;
    for (int t = w; t < T_; t += 8) {
      float v0 = sm.h[t][lane], v1 = sm.h[t][lane + 64];
      float s = v0 + v1;
      #pragma unroll
      for (int off = 32; off; off >>= 1) s += __shfl_xor(s, off, 64);
      float mean = s * (1.f / H_);
      float d0 = v0 - mean, d1 = v1 - mean;
      float q = d0 * d0 + d1 * d1;
      #pragma unroll
      for (int off = 32; off; off >>= 1) q += __shfl_xor(q, off, 64);
      float rstd = rsqrtf(q * (1.f / H_) + 1e-5f);
      sm.h[t][lane]      = d0 * rstd * l2g[lane]      + l2b[lane];
      sm.h[t][lane + 64] = d1 * rstd * l2g[lane + 64] + l2b[lane + 64];
    }
  }
  __syncthreads();

  if (tid < H_) t_repr[(size_t)seq * H_ + tid] = sm.h[T_ - 1][tid];
}

// s_repr[n][hh] = relu(x_static[n] . stat_w[hh] + stat_b[hh])
__global__ __launch_bounds__(256)
void k_static(const float* __restrict__ xst, const float* __restrict__ sw,
              const float* __restrict__ sb, float* __restrict__ s_repr)
{
  int idx = blockIdx.x * 256 + threadIdx.x;   // 512*128
  int n = idx >> 7, hh = idx & 127;
  float s = sb[hh];
  #pragma unroll
  for (int c = 0; c < S_; ++c) s += xst[n * S_ + c] * sw[hh * S_ + c];
  s_repr[idx] = fmaxf(s, 0.f);
}

// gh[b,n,:] = node @ gat_w^T ; ga1/ga2 = gh . a1 / a2
__global__ __launch_bounds__(128)
void k_gatproj(const float* __restrict__ t_repr, const float* __restrict__ s_repr,
               const float* __restrict__ gat_w, const float* __restrict__ gat_a,
               float* __restrict__ gh, float* __restrict__ ga1, float* __restrict__ ga2)
{
  int bi = blockIdx.x;            // b*512+n
  int n = bi & (N_ - 1);
  int hh = threadIdx.x;
  const float* wr = gat_w + hh * 2 * H_;
  float s = dot128(t_repr + (size_t)bi * H_, wr) +
            dot128(s_repr + (size_t)n * H_, wr + H_);
  gh[(size_t)bi * H_ + hh] = s;
  float c1 = s * gat_a[hh];
  float c2 = s * gat_a[H_ + hh];
  #pragma unroll
  for (int off = 32; off; off >>= 1) {
    c1 += __shfl_xor(c1, off, 64);
    c2 += __shfl_xor(c2, off, 64);
  }
  __shared__ float r1[2], r2[2];
  int w = hh >> 6;
  if ((hh & 63) == 0) { r1[w] = c1; r2[w] = c2; }
  __syncthreads();
  if (hh == 0) { ga1[bi] = r1[0] + r1[1]; ga2[bi] = r2[0] + r2[1]; }
}

// per (b,i): e-row -> softmax -> alpha out; g_repr; fused; heads
__global__ __launch_bounds__(256)
void k_gat(const int* __restrict__ adj, const float* __restrict__ gh,
           const float* __restrict__ ga1, const float* __restrict__ ga2,
           const float* __restrict__ t_repr, const float* __restrict__ s_repr,
           const float* __restrict__ fw, const float* __restrict__ fb,
           const float* __restrict__ regw, const float* __restrict__ regb,
           const float* __restrict__ riskw, const float* __restrict__ riskb,
           const float* __restrict__ warnw, const float* __restrict__ warnb,
           float* __restrict__ out_alpha, float* __restrict__ out_reg,
           float* __restrict__ out_risk, float* __restrict__ out_warn)
{
  const int row = blockIdx.x;     // b*512 + i
  const int bb = row >> 9, i = row & (N_ - 1);
  const int tid = threadIdx.x;
  __shared__ float ev[N_];
  alignas(16) __shared__ float gr[H_];
  alignas(16) __shared__ float fus[H_];
  __shared__ float red[4];

  const float g1 = ga1[row];
  const float* g2 = ga2 + (size_t)bb * N_;
  float lmax = -1e30f;
  for (int j = tid; j < N_; j += 256) {
    float e = g1 + g2[j];
    e = e > 0.f ? e : 0.2f * e;               // leaky_relu(0.2)
    if (adj[i * N_ + j] == 0) e = -1e30f;     // mask
    ev[j] = e; lmax = fmaxf(lmax, e);
  }
  #pragma unroll
  for (int off = 32; off; off >>= 1) lmax = fmaxf(lmax, __shfl_xor(lmax, off, 64));
  if ((tid & 63) == 0) red[tid >> 6] = lmax;
  __syncthreads();
  const float m = fmaxf(fmaxf(red[0], red[1]), fmaxf(red[2], red[3]));
  float lsum = 0.f;
  for (int j = tid; j < N_; j += 256) {
    float p = __expf(ev[j] - m);
    ev[j] = p; lsum += p;
  }
  #pragma unroll
  for (int off = 32; off; off >>= 1) lsum += __shfl_xor(lsum, off, 64);
  __syncthreads();                             // all have read red (max)
  if ((tid & 63) == 0) red[tid >> 6] = lsum;
  __syncthreads();
  const float inv = 1.f / (red[0] + red[1] + red[2] + red[3]);
  for (int j = tid; j < N_; j += 256) {
    float a = ev[j] * inv;
    ev[j] = a;
    out_alpha[(size_t)row * N_ + j] = a;
  }
  __syncthreads();

  if (tid < H_) {                              // g_repr[hh] = sum_j alpha_j * gh[b,j,hh]
    float acc = 0.f;
    const float* ghb = gh + (size_t)bb * N_ * H_ + tid;
    for (int j = 0; j < N_; ++j) acc += ev[j] * ghb[(size_t)j * H_];
    gr[tid] = acc;
  }
  __syncthreads();
  if (tid < H_) {                              // fused = relu([t_repr, s_repr, g_repr] @ fuse_w^T + b)
    const float* wr = fw + tid * 3 * H_;
    float s = fb[tid] +
              dot128(t_repr + (size_t)row * H_, wr) +
              dot128(s_repr + (size_t)i * H_, wr + H_) +
              dot128(gr, wr + 2 * H_);
    fus[tid] = fmaxf(s, 0.f);
  }
  __syncthreads();
  if (tid < 30) {                              // heads: 6 reg, 18 risk, 6 warn
    const float *wp, *bp; float* op; int o;
    if (tid < 6)       { o = tid;      wp = regw  + o * H_; bp = regb  + o; op = out_reg  + (size_t)row * 6  + o; }
    else if (tid < 24) { o = tid - 6;  wp = riskw + o * H_; bp = riskb + o; op = out_risk + (size_t)row * 18 + o; }
    else               { o = tid - 24; wp = warnw + o * H_; bp = warnb + o; op = out_warn + (size_t)row * 6  + o; }
    float s = *bp + dot128(fus, wp);
    *op = s;
  }
}

extern "C" void kernel_launch(void* const* d_in, const int* in_sizes, int n_in,
                              void* d_out, int out_size, void* d_ws, size_t ws_size,
                              hipStream_t stream)
{
  const float* x    = (const float*)d_in[0];
  const float* xst  = (const float*)d_in[1];
  const int*   adj  = (const int*)d_in[2];
  const float* pw   = (const float*)d_in[3];
  const float* pb   = (const float*)d_in[4];
  const float* inw  = (const float*)d_in[5];
  const float* inb  = (const float*)d_in[6];
  const float* ow   = (const float*)d_in[7];
  const float* ob   = (const float*)d_in[8];
  const float* l1g  = (const float*)d_in[9];
  const float* l1b  = (const float*)d_in[10];
  const float* w1   = (const float*)d_in[11];
  const float* b1   = (const float*)d_in[12];
  const float* w2   = (const float*)d_in[13];
  const float* b2   = (const float*)d_in[14];
  const float* l2g  = (const float*)d_in[15];
  const float* l2b  = (const float*)d_in[16];
  const float* stw  = (const float*)d_in[17];
  const float* stb  = (const float*)d_in[18];
  const float* gatw = (const float*)d_in[19];
  const float* gata = (const float*)d_in[20];
  const float* fw   = (const float*)d_in[21];
  const float* fb   = (const float*)d_in[22];
  const float* regw = (const float*)d_in[23];
  const float* regb = (const float*)d_in[24];
  const float* rkw  = (const float*)d_in[25];
  const float* rkb  = (const float*)d_in[26];
  const float* wnw  = (const float*)d_in[27];
  const float* wnb  = (const float*)d_in[28];

  float* out       = (float*)d_out;
  float* out_reg   = out;                 // 24576
  float* out_risk  = out + 24576;         // 73728
  float* out_warn  = out + 98304;         // 24576
  float* out_tatt  = out + 122880;        // 9437184
  float* out_alpha = out + 9560064;       // 2097152

  float* ws     = (float*)d_ws;           // ~4.5MB f32 scratch
  float* t_repr = ws;                     // 4096*128
  float* s_repr = ws + 524288;            // 512*128
  float* gh     = ws + 589824;            // 4096*128
  float* ga1    = ws + 1114112;           // 4096
  float* ga2    = ws + 1118208;           // 4096

  k_seq<<<dim3(B_ * N_), dim3(512), 0, stream>>>(
      x, pw, pb, inw, inb, ow, ob, l1g, l1b, w1, b1, w2, b2, l2g, l2b,
      out_tatt, t_repr);
  k_static<<<dim3(256), dim3(256), 0, stream>>>(xst, stw, stb, s_repr);
  k_gatproj<<<dim3(B_ * N_), dim3(128), 0, stream>>>(
      t_repr, s_repr, gatw, gata, gh, ga1, ga2);
  k_gat<<<dim3(B_ * N_), dim3(256), 0, stream>>>(
      adj, gh, ga1, ga2, t_repr, s_repr, fw, fb,
      regw, regb, rkw, rkb, wnw, wnb,
      out_alpha, out_reg, out_risk, out_warn);
}

// Round 5
// 2543.028 us; speedup vs baseline: 4.5764x; 4.5764x over previous
//
#include <hip/hip_runtime.h>

// DustRiskFormer: B=8 T=48 N=512 F=16 S=12 H=128 NH=8 HZ=6 NC=3
// All float tensors f32; adj int32.
// Outputs (f32, concat flat): reg[8,512,6] risk[8,512,6,3] warn[8,512,6]
//                             t_attn[4096,48,48] alpha[8,512,512]
// R4: k_seq GEMMs register-blocked (thread = col-cluster x t-group) to kill
//     the 102 GB uncoalesced L2 weight re-read (VALUBusy was 11%).

#define B_ 8
#define T_ 48
#define N_ 512
#define F_ 16
#define S_ 12
#define H_ 128
#define NH_ 8
#define HD_ 16

__device__ __forceinline__ float dot128(const float* __restrict__ a,
                                        const float* __restrict__ w) {
  float s = 0.f;
  #pragma unroll 8
  for (int c = 0; c < 32; ++c) {
    float4 av = *(const float4*)(a + 4 * c);
    float4 wv = *(const float4*)(w + 4 * c);
    s += av.x * wv.x + av.y * wv.y + av.z * wv.z + av.w * wv.w;
  }
  return s;
}

struct AttnBufs {
  float qk[2][T_][H_];      // 48KB (q,k f32)
  float v[T_][H_];          // 24KB
  float tatt[T_][T_];       // 9KB
};
struct alignas(16) SmemA {
  float h[T_][H_];          // 24KB  hidden state (residual-carrying)
  float attn[T_][H_];       // 24KB  attention output
  float xs[T_][F_];         // 3KB
  union { AttnBufs a; float g[T_][2 * H_]; } u;  // max 81KB
};                          // total ~132KB -> 1 block/CU, 8 waves

__global__ __launch_bounds__(512, 1)
void k_seq(const float* __restrict__ x,
           const float* __restrict__ pw,  const float* __restrict__ pb,
           const float* __restrict__ in_w, const float* __restrict__ in_b,
           const float* __restrict__ ow,  const float* __restrict__ ob,
           const float* __restrict__ l1g, const float* __restrict__ l1b,
           const float* __restrict__ w1,  const float* __restrict__ b1,
           const float* __restrict__ w2,  const float* __restrict__ b2,
           const float* __restrict__ l2g, const float* __restrict__ l2b,
           float* __restrict__ out_tatt, float* __restrict__ t_repr)
{
  __shared__ SmemA sm;
  const int seq = blockIdx.x;
  const int b = seq >> 9, n = seq & (N_ - 1);
  const int tid = threadIdx.x;

  // load x[b, :, n, :]  (48x16) and zero tatt
  for (int i = tid; i < T_ * F_; i += 512) {
    int t = i >> 4, f = i & 15;
    sm.xs[t][f] = x[((size_t)(b * T_ + t) * N_ + n) * F_ + f];
  }
  for (int i = tid; i < T_ * T_; i += 512) (&sm.u.a.tatt[0][0])[i] = 0.f;
  __syncthreads();

  // h = xs @ proj_w^T + proj_b   (48x128, K=16 — tiny, keep simple)
  for (int i = tid; i < T_ * H_; i += 512) {
    int t = i >> 7, hh = i & 127;
    float s = pb[hh];
    const float* wr = pw + hh * F_;
    #pragma unroll
    for (int f = 0; f < F_; ++f) s += sm.xs[t][f] * wr[f];
    sm.h[t][hh] = s;
  }
  __syncthreads();

  // ---- qkv = h @ in_w^T + in_b  (48x384, K=128) ----
  // thread: cluster c (3 cols: 3c..3c+2) x t-group tg (12 rows). 128x4=512 thr.
  {
    const int c  = tid & 127;
    const int tg = tid >> 7;              // 0..3
    const int o0 = c * 3;
    const int t0 = tg * 12;
    float acc0[12], acc1[12], acc2[12];
    #pragma unroll
    for (int tt = 0; tt < 12; ++tt) { acc0[tt] = 0.f; acc1[tt] = 0.f; acc2[tt] = 0.f; }
    const float* wr0 = in_w + (size_t)(o0 + 0) * H_;
    const float* wr1 = in_w + (size_t)(o0 + 1) * H_;
    const float* wr2 = in_w + (size_t)(o0 + 2) * H_;
    for (int kk = 0; kk < 32; ++kk) {
      float4 wa = *(const float4*)(wr0 + 4 * kk);
      float4 wb = *(const float4*)(wr1 + 4 * kk);
      float4 wc = *(const float4*)(wr2 + 4 * kk);
      #pragma unroll
      for (int tt = 0; tt < 12; ++tt) {
        float4 hv = *(const float4*)(&sm.h[t0 + tt][4 * kk]);   // wave-broadcast
        acc0[tt] += wa.x * hv.x + wa.y * hv.y + wa.z * hv.z + wa.w * hv.w;
        acc1[tt] += wb.x * hv.x + wb.y * hv.y + wb.z * hv.z + wb.w * hv.w;
        acc2[tt] += wc.x * hv.x + wc.y * hv.y + wc.z * hv.z + wc.w * hv.w;
      }
    }
    #pragma unroll
    for (int cc = 0; cc < 3; ++cc) {
      const int o = o0 + cc;
      const int j = o >> 7, hh = o & 127;
      const float bias = in_b[o];
      #pragma unroll
      for (int tt = 0; tt < 12; ++tt) {
        float s = (cc == 0 ? acc0[tt] : cc == 1 ? acc1[tt] : acc2[tt]) + bias;
        if (j == 2) sm.u.a.v[t0 + tt][hh] = s;
        else        sm.u.a.qk[j][t0 + tt][hh] = s;
      }
    }
  }
  __syncthreads();

  // attention: wave w = head w; lane r < 48 owns query-row r; scores in registers
  {
    const int w = tid >> 6, lane = tid & 63;
    if (lane < T_) {
      const int r = lane;
      float qv[HD_];
      #pragma unroll
      for (int d = 0; d < HD_; ++d) qv[d] = sm.u.a.qk[0][r][w * HD_ + d] * 0.25f;
      float sc[T_];
      float m = -1e30f;
      #pragma unroll
      for (int k = 0; k < T_; ++k) {
        float s = 0.f;
        #pragma unroll
        for (int d = 0; d < HD_; ++d) s += qv[d] * sm.u.a.qk[1][k][w * HD_ + d];
        sc[k] = s; m = fmaxf(m, s);
      }
      float sum = 0.f;
      #pragma unroll
      for (int k = 0; k < T_; ++k) { float p = __expf(sc[k] - m); sc[k] = p; sum += p; }
      float inv = 1.f / sum;
      #pragma unroll
      for (int k = 0; k < T_; ++k) {
        sc[k] *= inv;
        atomicAdd(&sm.u.a.tatt[r][k], sc[k] * 0.125f);   // mean over 8 heads
      }
      #pragma unroll
      for (int d = 0; d < HD_; ++d) {
        float acc = 0.f;
        #pragma unroll
        for (int k = 0; k < T_; ++k) acc += sc[k] * sm.u.a.v[k][w * HD_ + d];
        sm.attn[r][w * HD_ + d] = acc;
      }
    }
  }
  __syncthreads();

  // write t_attn
  for (int i = tid; i < T_ * T_; i += 512)
    out_tatt[(size_t)seq * T_ * T_ + i] = (&sm.u.a.tatt[0][0])[i];

  // ---- out-proj + residual: h += attn @ ow^T + ob  (48x128, K=128) ----
  // cluster c (2 cols) x 8 t-groups (6 rows). 64x8=512 thr.
  {
    const int c  = tid & 63;
    const int tg = tid >> 6;              // 0..7
    const int o0 = c * 2;
    const int t0 = tg * 6;
    float acc0[6], acc1[6];
    #pragma unroll
    for (int tt = 0; tt < 6; ++tt) { acc0[tt] = 0.f; acc1[tt] = 0.f; }
    const float* wr0 = ow + (size_t)(o0 + 0) * H_;
    const float* wr1 = ow + (size_t)(o0 + 1) * H_;
    for (int kk = 0; kk < 32; ++kk) {
      float4 wa = *(const float4*)(wr0 + 4 * kk);
      float4 wb = *(const float4*)(wr1 + 4 * kk);
      #pragma unroll
      for (int tt = 0; tt < 6; ++tt) {
        float4 hv = *(const float4*)(&sm.attn[t0 + tt][4 * kk]);
        acc0[tt] += wa.x * hv.x + wa.y * hv.y + wa.z * hv.z + wa.w * hv.w;
        acc1[tt] += wb.x * hv.x + wb.y * hv.y + wb.z * hv.z + wb.w * hv.w;
      }
    }
    const float b0 = ob[o0], b1v = ob[o0 + 1];
    #pragma unroll
    for (int tt = 0; tt < 6; ++tt) {
      sm.h[t0 + tt][o0]     += acc0[tt] + b0;
      sm.h[t0 + tt][o0 + 1] += acc1[tt] + b1v;
    }
  }
  __syncthreads();

  // LN1 (wave per row; lane covers elems lane, lane+64)
  {
    const int w = tid >> 6, lane = tid & 63;
    for (int t = w; t < T_; t += 8) {
      float v0 = sm.h[t][lane], v1 = sm.h[t][lane + 64];
      float s = v0 + v1;
      #pragma unroll
      for (int off = 32; off; off >>= 1) s += __shfl_xor(s, off, 64);
      float mean = s * (1.f / H_);
      float d0 = v0 - mean, d1 = v1 - mean;
      float q = d0 * d0 + d1 * d1;
      #pragma unroll
      for (int off = 32; off; off >>= 1) q += __shfl_xor(q, off, 64);
      float rstd = rsqrtf(q * (1.f / H_) + 1e-5f);
      sm.h[t][lane]      = d0 * rstd * l1g[lane]      + l1b[lane];
      sm.h[t][lane + 64] = d1 * rstd * l1g[lane + 64] + l1b[lane + 64];
    }
  }
  __syncthreads();

  // ---- FFN1: g = gelu(h @ w1^T + b1)  (48x256, K=128) ----
  // cluster c (2 cols of 256) x 4 t-groups (12 rows). 128x4=512 thr.
  {
    const int c  = tid & 127;
    const int tg = tid >> 7;              // 0..3
    const int o0 = c * 2;
    const int t0 = tg * 12;
    float acc0[12], acc1[12];
    #pragma unroll
    for (int tt = 0; tt < 12; ++tt) { acc0[tt] = 0.f; acc1[tt] = 0.f; }
    const float* wr0 = w1 + (size_t)(o0 + 0) * H_;
    const float* wr1 = w1 + (size_t)(o0 + 1) * H_;
    for (int kk = 0; kk < 32; ++kk) {
      float4 wa = *(const float4*)(wr0 + 4 * kk);
      float4 wb = *(const float4*)(wr1 + 4 * kk);
      #pragma unroll
      for (int tt = 0; tt < 12; ++tt) {
        float4 hv = *(const float4*)(&sm.h[t0 + tt][4 * kk]);
        acc0[tt] += wa.x * hv.x + wa.y * hv.y + wa.z * hv.z + wa.w * hv.w;
        acc1[tt] += wb.x * hv.x + wb.y * hv.y + wb.z * hv.z + wb.w * hv.w;
      }
    }
    const float b0 = b1[o0], b1v = b1[o0 + 1];
    #pragma unroll
    for (int tt = 0; tt < 12; ++tt) {
      float s0 = acc0[tt] + b0;
      float s1 = acc1[tt] + b1v;
      sm.u.g[t0 + tt][o0]     = 0.5f * s0 * (1.f + erff(s0 * 0.70710678118f));
      sm.u.g[t0 + tt][o0 + 1] = 0.5f * s1 * (1.f + erff(s1 * 0.70710678118f));
    }
  }
  __syncthreads();

  // ---- FFN2 + residual: h += g @ w2^T + b2  (48x128, K=256) ----
  // cluster c (2 cols) x 8 t-groups (6 rows). 64x8=512 thr.
  {
    const int c  = tid & 63;
    const int tg = tid >> 6;              // 0..7
    const int o0 = c * 2;
    const int t0 = tg * 6;
    float acc0[6], acc1[6];
    #pragma unroll
    for (int tt = 0; tt < 6; ++tt) { acc0[tt] = 0.f; acc1[tt] = 0.f; }
    const float* wr0 = w2 + (size_t)(o0 + 0) * 2 * H_;
    const float* wr1 = w2 + (size_t)(o0 + 1) * 2 * H_;
    for (int kk = 0; kk < 64; ++kk) {
      float4 wa = *(const float4*)(wr0 + 4 * kk);
      float4 wb = *(const float4*)(wr1 + 4 * kk);
      #pragma unroll
      for (int tt = 0; tt < 6; ++tt) {
        float4 hv = *(const float4*)(&sm.u.g[t0 + tt][4 * kk]);
        acc0[tt] += wa.x * hv.x + wa.y * hv.y + wa.z * hv.z + wa.w * hv.w;
        acc1[tt] += wb.x * hv.x + wb.y * hv.y + wb.z * hv.z + wb.w * hv.w;
      }
    }
    const float b0 = b2[o0], b1v = b2[o0 + 1];
    #pragma unroll
    for (int tt = 0; tt < 6; ++tt) {
      sm.h[t0 + tt][o0]     += acc0[tt] + b0;
      sm.h[t0 + tt][o0 + 1] += acc1[tt] + b1v;
    }
  }
  __syncthreads();

  // LN2
  {
    const int w = tid >> 6, lane = tid & 63;
    for (int t = w; t < T_; t += 8) {
      float v0 = sm.h[t][lane], v1 = sm.h[t][lane + 64];
      float s = v0 + v1;
      #pragma unroll
      for (int off = 32; off; off >>= 1) s += __shfl_xor(s, off, 64);
      float mean = s * (1.f / H_);
      float d0 = v0 - mean, d1 = v1 - mean;
      float q = d0 * d0 + d1 * d1;
      #pragma unroll
      for (int off = 32; off; off >>= 1) q += __shfl_xor(q, off, 64);
      float rstd = rsqrtf(q * (1.f / H_) + 1e-5f);
      sm.h[t][lane]      = d0 * rstd * l2g[lane]      + l2b[lane];
      sm.h[t][lane + 64] = d1 * rstd * l2g[lane + 64] + l2b[lane + 64];
    }
  }
  __syncthreads();

  if (tid < H_) t_repr[(size_t)seq * H_ + tid] = sm.h[T_ - 1][tid];
}

// s_repr[n][hh] = relu(x_static[n] . stat_w[hh] + stat_b[hh])
__global__ __launch_bounds__(256)
void k_static(const float* __restrict__ xst, const float* __restrict__ sw,
              const float* __restrict__ sb, float* __restrict__ s_repr)
{
  int idx = blockIdx.x * 256 + threadIdx.x;   // 512*128
  int n = idx >> 7, hh = idx & 127;
  float s = sb[hh];
  #pragma unroll
  for (int c = 0; c < S_; ++c) s += xst[n * S_ + c] * sw[hh * S_ + c];
  s_repr[idx] = fmaxf(s, 0.f);
}

// gh[b,n,:] = node @ gat_w^T ; ga1/ga2 = gh . a1 / a2
__global__ __launch_bounds__(128)
void k_gatproj(const float* __restrict__ t_repr, const float* __restrict__ s_repr,
               const float* __restrict__ gat_w, const float* __restrict__ gat_a,
               float* __restrict__ gh, float* __restrict__ ga1, float* __restrict__ ga2)
{
  int bi = blockIdx.x;            // b*512+n
  int n = bi & (N_ - 1);
  int hh = threadIdx.x;
  const float* wr = gat_w + hh * 2 * H_;
  float s = dot128(t_repr + (size_t)bi * H_, wr) +
            dot128(s_repr + (size_t)n * H_, wr + H_);
  gh[(size_t)bi * H_ + hh] = s;
  float c1 = s * gat_a[hh];
  float c2 = s * gat_a[H_ + hh];
  #pragma unroll
  for (int off = 32; off; off >>= 1) {
    c1 += __shfl_xor(c1, off, 64);
    c2 += __shfl_xor(c2, off, 64);
  }
  __shared__ float r1[2], r2[2];
  int w = hh >> 6;
  if ((hh & 63) == 0) { r1[w] = c1; r2[w] = c2; }
  __syncthreads();
  if (hh == 0) { ga1[bi] = r1[0] + r1[1]; ga2[bi] = r2[0] + r2[1]; }
}

// per (b,i): e-row -> softmax -> alpha out; g_repr; fused; heads
__global__ __launch_bounds__(256)
void k_gat(const int* __restrict__ adj, const float* __restrict__ gh,
           const float* __restrict__ ga1, const float* __restrict__ ga2,
           const float* __restrict__ t_repr, const float* __restrict__ s_repr,
           const float* __restrict__ fw, const float* __restrict__ fb,
           const float* __restrict__ regw, const float* __restrict__ regb,
           const float* __restrict__ riskw, const float* __restrict__ riskb,
           const float* __restrict__ warnw, const float* __restrict__ warnb,
           float* __restrict__ out_alpha, float* __restrict__ out_reg,
           float* __restrict__ out_risk, float* __restrict__ out_warn)
{
  const int row = blockIdx.x;     // b*512 + i
  const int bb = row >> 9, i = row & (N_ - 1);
  const int tid = threadIdx.x;
  __shared__ float ev[N_];
  alignas(16) __shared__ float gr[H_];
  alignas(16) __shared__ float fus[H_];
  __shared__ float red[4];

  const float g1 = ga1[row];
  const float* g2 = ga2 + (size_t)bb * N_;
  float lmax = -1e30f;
  for (int j = tid; j < N_; j += 256) {
    float e = g1 + g2[j];
    e = e > 0.f ? e : 0.2f * e;               // leaky_relu(0.2)
    if (adj[i * N_ + j] == 0) e = -1e30f;     // mask
    ev[j] = e; lmax = fmaxf(lmax, e);
  }
  #pragma unroll
  for (int off = 32; off; off >>= 1) lmax = fmaxf(lmax, __shfl_xor(lmax, off, 64));
  if ((tid & 63) == 0) red[tid >> 6] = lmax;
  __syncthreads();
  const float m = fmaxf(fmaxf(red[0], red[1]), fmaxf(red[2], red[3]));
  float lsum = 0.f;
  for (int j = tid; j < N_; j += 256) {
    float p = __expf(ev[j] - m);
    ev[j] = p; lsum += p;
  }
  #pragma unroll
  for (int off = 32; off; off >>= 1) lsum += __shfl_xor(lsum, off, 64);
  __syncthreads();                             // all have read red (max)
  if ((tid & 63) == 0) red[tid >> 6] = lsum;
  __syncthreads();
  const float inv = 1.f / (red[0] + red[1] + red[2] + red[3]);
  for (int j = tid; j < N_; j += 256) {
    float a = ev[j] * inv;
    ev[j] = a;
    out_alpha[(size_t)row * N_ + j] = a;
  }
  __syncthreads();

  if (tid < H_) {                              // g_repr[hh] = sum_j alpha_j * gh[b,j,hh]
    float acc = 0.f;
    const float* ghb = gh + (size_t)bb * N_ * H_ + tid;
    for (int j = 0; j < N_; ++j) acc += ev[j] * ghb[(size_t)j * H_];
    gr[tid] = acc;
  }
  __syncthreads();
  if (tid < H_) {                              // fused = relu([t_repr, s_repr, g_repr] @ fuse_w^T + b)
    const float* wr = fw + tid * 3 * H_;
    float s = fb[tid] +
              dot128(t_repr + (size_t)row * H_, wr) +
              dot128(s_repr + (size_t)i * H_, wr + H_) +
              dot128(gr, wr + 2 * H_);
    fus[tid] = fmaxf(s, 0.f);
  }
  __syncthreads();
  if (tid < 30) {                              // heads: 6 reg, 18 risk, 6 warn
    const float *wp, *bp; float* op; int o;
    if (tid < 6)       { o = tid;      wp = regw  + o * H_; bp = regb  + o; op = out_reg  + (size_t)row * 6  + o; }
    else if (tid < 24) { o = tid - 6;  wp = riskw + o * H_; bp = riskb + o; op = out_risk + (size_t)row * 18 + o; }
    else               { o = tid - 24; wp = warnw + o * H_; bp = warnb + o; op = out_warn + (size_t)row * 6  + o; }
    float s = *bp + dot128(fus, wp);
    *op = s;
  }
}

extern "C" void kernel_launch(void* const* d_in, const int* in_sizes, int n_in,
                              void* d_out, int out_size, void* d_ws, size_t ws_size,
                              hipStream_t stream)
{
  const float* x    = (const float*)d_in[0];
  const float* xst  = (const float*)d_in[1];
  const int*   adj  = (const int*)d_in[2];
  const float* pw   = (const float*)d_in[3];
  const float* pb   = (const float*)d_in[4];
  const float* inw  = (const float*)d_in[5];
  const float* inb  = (const float*)d_in[6];
  const float* ow   = (const float*)d_in[7];
  const float* ob   = (const float*)d_in[8];
  const float* l1g  = (const float*)d_in[9];
  const float* l1b  = (const float*)d_in[10];
  const float* w1   = (const float*)d_in[11];
  const float* b1   = (const float*)d_in[12];
  const float* w2   = (const float*)d_in[13];
  const float* b2   = (const float*)d_in[14];
  const float* l2g  = (const float*)d_in[15];
  const float* l2b  = (const float*)d_in[16];
  const float* stw  = (const float*)d_in[17];
  const float* stb  = (const float*)d_in[18];
  const float* gatw = (const float*)d_in[19];
  const float* gata = (const float*)d_in[20];
  const float* fw   = (const float*)d_in[21];
  const float* fb   = (const float*)d_in[22];
  const float* regw = (const float*)d_in[23];
  const float* regb = (const float*)d_in[24];
  const float* rkw  = (const float*)d_in[25];
  const float* rkb  = (const float*)d_in[26];
  const float* wnw  = (const float*)d_in[27];
  const float* wnb  = (const float*)d_in[28];

  float* out       = (float*)d_out;
  float* out_reg   = out;                 // 24576
  float* out_risk  = out + 24576;         // 73728
  float* out_warn  = out + 98304;         // 24576
  float* out_tatt  = out + 122880;        // 9437184
  float* out_alpha = out + 9560064;       // 2097152

  float* ws     = (float*)d_ws;           // ~4.5MB f32 scratch
  float* t_repr = ws;                     // 4096*128
  float* s_repr = ws + 524288;            // 512*128
  float* gh     = ws + 589824;            // 4096*128
  float* ga1    = ws + 1114112;           // 4096
  float* ga2    = ws + 1118208;           // 4096

  k_seq<<<dim3(B_ * N_), dim3(512), 0, stream>>>(
      x, pw, pb, inw, inb, ow, ob, l1g, l1b, w1, b1, w2, b2, l2g, l2b,
      out_tatt, t_repr);
  k_static<<<dim3(256), dim3(256), 0, stream>>>(xst, stw, stb, s_repr);
  k_gatproj<<<dim3(B_ * N_), dim3(128), 0, stream>>>(
      t_repr, s_repr, gatw, gata, gh, ga1, ga2);
  k_gat<<<dim3(B_ * N_), dim3(256), 0, stream>>>(
      adj, gh, ga1, ga2, t_repr, s_repr, fw, fb,
      regw, regb, rkw, rkb, wnw, wnb,
      out_alpha, out_reg, out_risk, out_warn);
}

// Round 7
// 1131.064 us; speedup vs baseline: 10.2894x; 2.2483x over previous
//
#include <hip/hip_runtime.h>

// DustRiskFormer: B=8 T=48 N=512 F=16 S=12 H=128 NH=8 HZ=6 NC=3
// All float tensors f32; adj int32.
// Outputs (f32, concat flat): reg[8,512,6] risk[8,512,6,3] warn[8,512,6]
//                             t_attn[4096,48,48] alpha[8,512,512]
// R5: 4 big GEMMs -> v_mfma_f32_16x16x32_bf16 (weights prepacked bf16 by k_prep,
//     activations via XOR-swizzled bf16 LDS). tatt pad 49 + wave-stagger kills
//     the 24-way atomic bank conflict. float4 attention reads.
// R6: wpk aliases the gh scratch region (disjoint lifetime) so total d_ws use
//     stays at the proven 4,489,216 bytes — guards against ws_size OOB fault.

#define B_ 8
#define T_ 48
#define N_ 512
#define F_ 16
#define S_ 12
#define H_ 128
#define NH_ 8
#define HD_ 16

typedef unsigned short ushort_t;
typedef short bf16x8 __attribute__((ext_vector_type(8)));
typedef float f32x4 __attribute__((ext_vector_type(4)));

__device__ __forceinline__ ushort_t f2us(float f) {
  union { float f; unsigned int i; } v; v.f = f;
  unsigned int r = v.i + 0x7FFFu + ((v.i >> 16) & 1u);   // RNE
  return (ushort_t)(r >> 16);
}
__device__ __forceinline__ unsigned int pk2(float a, float b) {
  return (unsigned int)f2us(a) | ((unsigned int)f2us(b) << 16);
}
__device__ __forceinline__ float dot128(const float* __restrict__ a,
                                        const float* __restrict__ w) {
  float s = 0.f;
  #pragma unroll 8
  for (int c = 0; c < 32; ++c) {
    float4 av = *(const float4*)(a + 4 * c);
    float4 wv = *(const float4*)(w + 4 * c);
    s += av.x * wv.x + av.y * wv.y + av.z * wv.z + av.w * wv.w;
  }
  return s;
}

#define MFMA16(a, b, c) __builtin_amdgcn_mfma_f32_16x16x32_bf16(a, b, c, 0, 0, 0)

// -------- weight pre-pack: f32 -> bf16 in MFMA A-fragment order --------
// A-frag (weights as A): lane l holds row mt*16+(l&15), k = ks*32+(l>>4)*8+j
// packed[((mt*KS+ks)*64+lane)*8 + j]
__global__ __launch_bounds__(256)
void k_prep(const float* __restrict__ inw, const float* __restrict__ ow,
            const float* __restrict__ w1,  const float* __restrict__ w2,
            ushort_t* __restrict__ wp)
{
  int i = blockIdx.x * 256 + threadIdx.x;     // 131072 total
  const float* src; int K, base;
  if (i < 49152)      { src = inw; K = 128; base = 0;     }
  else if (i < 65536) { src = ow;  K = 128; base = 49152; }
  else if (i < 98304) { src = w1;  K = 128; base = 65536; }
  else                { src = w2;  K = 256; base = 98304; }
  int rel  = i - base;
  int j    = rel & 7;
  int lane = (rel >> 3) & 63;
  int tile = rel >> 9;
  int KS   = K >> 5;
  int mt   = tile / KS, ks = tile - mt * KS;
  int row  = mt * 16 + (lane & 15);
  int k    = ks * 32 + ((lane >> 4) & 3) * 8 + j;
  wp[i] = f2us(src[(size_t)row * K + k]);
}

struct alignas(16) SmemA {
  float    h[T_][132];          // 25.3KB hidden (residual), padded
  ushort_t hb[T_][H_];          // 12KB   bf16 GEMM input, XOR-swizzled
  float    xs[T_][F_];          // 3KB
  float    tatt[T_][49];        // 9.2KB  padded -> atomic banks spread
  float    attn[T_][132];       // 25.3KB attention output
  union {
    struct { float qk[2][T_][132]; float v[T_][132]; } a;  // 76KB
    ushort_t gb[T_][2 * H_];    // 24KB   FFN hidden bf16, XOR-swizzled
  } u;
};                              // ~148KB -> 1 block/CU

__global__ __launch_bounds__(512, 1)
void k_seq(const float* __restrict__ x,
           const float* __restrict__ pw,  const float* __restrict__ pb,
           const float* __restrict__ in_b, const float* __restrict__ ob,
           const float* __restrict__ l1g, const float* __restrict__ l1b,
           const float* __restrict__ b1,  const float* __restrict__ b2,
           const float* __restrict__ l2g, const float* __restrict__ l2b,
           const ushort_t* __restrict__ wpk,
           float* __restrict__ out_tatt, float* __restrict__ t_repr)
{
  __shared__ SmemA sm;
  const int seq = blockIdx.x;
  const int b = seq >> 9, n = seq & (N_ - 1);
  const int tid = threadIdx.x;
  const int wv = tid >> 6, ln = tid & 63;
  const int lg = ln >> 4, lr = ln & 15;

  const ushort_t* wp_in = wpk;            // 24 mt x 4 ks
  const ushort_t* wp_ow = wpk + 49152;    // 8 x 4
  const ushort_t* wp_w1 = wpk + 65536;    // 16 x 4
  const ushort_t* wp_w2 = wpk + 98304;    // 8 x 8

  // ---- load x[b,:,n,:], zero tatt ----
  for (int i = tid; i < T_ * F_; i += 512) {
    int t = i >> 4, f = i & 15;
    sm.xs[t][f] = x[((size_t)(b * T_ + t) * N_ + n) * F_ + f];
  }
  for (int i = tid; i < T_ * 49; i += 512) (&sm.tatt[0][0])[i] = 0.f;
  __syncthreads();

  // ---- proj: h = xs @ pw^T + pb  (K=16, tiny) ----
  for (int i = tid; i < T_ * H_; i += 512) {
    int t = i >> 7, hh = i & 127;
    float s = pb[hh];
    const float* wr = pw + hh * F_;
    #pragma unroll
    for (int f = 0; f < F_; ++f) s += sm.xs[t][f] * wr[f];
    sm.h[t][hh] = s;
  }
  __syncthreads();

  // ---- conv h -> hb (bf16, swizzled) ----
  if (tid < 384) {
    int t = tid >> 3, c0 = (tid & 7) * 16;
    const float* rp = &sm.h[t][c0];
    unsigned int u[8];
    #pragma unroll
    for (int q = 0; q < 8; ++q) u[q] = pk2(rp[2 * q], rp[2 * q + 1]);
    int base = t * 256 + c0 * 2, sw = (t & 7) << 4;
    *(uint4*)((char*)sm.hb + ((base) ^ sw))      = make_uint4(u[0], u[1], u[2], u[3]);
    *(uint4*)((char*)sm.hb + ((base + 16) ^ sw)) = make_uint4(u[4], u[5], u[6], u[7]);
  }
  __syncthreads();

  // ---- qkv MFMA: [384 out] x [48 t], K=128. wave: mt 3w..3w+2, nt 0..2 ----
  {
    f32x4 acc[3][3];
    #pragma unroll
    for (int i = 0; i < 3; ++i)
      #pragma unroll
      for (int j = 0; j < 3; ++j) acc[i][j] = (f32x4){0.f, 0.f, 0.f, 0.f};
    #pragma unroll
    for (int ks = 0; ks < 4; ++ks) {
      bf16x8 Af[3], Bf[3];
      #pragma unroll
      for (int i = 0; i < 3; ++i) {
        int mt = wv * 3 + i;
        Af[i] = *(const bf16x8*)(wp_in + (size_t)((mt * 4 + ks) * 64 + ln) * 8);
        int row = i * 16 + lr;
        Bf[i] = *(const bf16x8*)((const char*)sm.hb +
                 ((row * 256 + ks * 64 + lg * 16) ^ ((row & 7) << 4)));
      }
      #pragma unroll
      for (int i = 0; i < 3; ++i)
        #pragma unroll
        for (int j = 0; j < 3; ++j) acc[i][j] = MFMA16(Af[i], Bf[j], acc[i][j]);
    }
    #pragma unroll
    for (int i = 0; i < 3; ++i) {
      int mt = wv * 3 + i;
      int hh0 = mt * 16 + lg * 4;                 // global out index (0..383)
      float4 bias = *(const float4*)(in_b + hh0);
      #pragma unroll
      for (int j = 0; j < 3; ++j) {
        int t = j * 16 + lr;
        float4 o;
        o.x = acc[i][j].x + bias.x; o.y = acc[i][j].y + bias.y;
        o.z = acc[i][j].z + bias.z; o.w = acc[i][j].w + bias.w;
        if (hh0 < 128) {            // q (fold 1/sqrt(hd)=0.25)
          o.x *= 0.25f; o.y *= 0.25f; o.z *= 0.25f; o.w *= 0.25f;
          *(float4*)&sm.u.a.qk[0][t][hh0] = o;
        } else if (hh0 < 256) {     // k
          *(float4*)&sm.u.a.qk[1][t][hh0 - 128] = o;
        } else {                    // v
          *(float4*)&sm.u.a.v[t][hh0 - 256] = o;
        }
      }
    }
  }
  __syncthreads();

  // ---- attention (VALU): wave=head, lane r<48 = query row ----
  if (ln < T_) {
    const int r = ln;
    float4 qv[4];
    #pragma unroll
    for (int d4 = 0; d4 < 4; ++d4)
      qv[d4] = *(const float4*)&sm.u.a.qk[0][r][wv * 16 + d4 * 4];
    float sc[T_];
    float m = -1e30f;
    #pragma unroll 4
    for (int k = 0; k < T_; ++k) {
      float s = 0.f;
      #pragma unroll
      for (int d4 = 0; d4 < 4; ++d4) {
        float4 kv = *(const float4*)&sm.u.a.qk[1][k][wv * 16 + d4 * 4];
        s += qv[d4].x * kv.x + qv[d4].y * kv.y + qv[d4].z * kv.z + qv[d4].w * kv.w;
      }
      sc[k] = s; m = fmaxf(m, s);
    }
    float sum = 0.f;
    #pragma unroll
    for (int k = 0; k < T_; ++k) { float p = __expf(sc[k] - m); sc[k] = p; sum += p; }
    float inv = 1.f / sum;
    float4 acc[4];
    #pragma unroll
    for (int d4 = 0; d4 < 4; ++d4) acc[d4] = make_float4(0.f, 0.f, 0.f, 0.f);
    #pragma unroll 4
    for (int kk = 0; kk < T_; ++kk) {
      int k = kk + wv * 6; if (k >= T_) k -= T_;   // wave-stagger
      float p = sc[k] * inv;
      atomicAdd(&sm.tatt[r][k], p * 0.125f);
      #pragma unroll
      for (int d4 = 0; d4 < 4; ++d4) {
        float4 vv = *(const float4*)&sm.u.a.v[k][wv * 16 + d4 * 4];
        acc[d4].x += p * vv.x; acc[d4].y += p * vv.y;
        acc[d4].z += p * vv.z; acc[d4].w += p * vv.w;
      }
    }
    #pragma unroll
    for (int d4 = 0; d4 < 4; ++d4)
      *(float4*)&sm.attn[r][wv * 16 + d4 * 4] = acc[d4];
  }
  __syncthreads();

  // ---- tatt writeout + conv attn -> hb ----
  for (int i = tid; i < T_ * T_; i += 512) {
    int r = i / T_, k = i - r * T_;
    out_tatt[(size_t)seq * T_ * T_ + i] = sm.tatt[r][k];
  }
  if (tid < 384) {
    int t = tid >> 3, c0 = (tid & 7) * 16;
    const float* rp = &sm.attn[t][c0];
    unsigned int u[8];
    #pragma unroll
    for (int q = 0; q < 8; ++q) u[q] = pk2(rp[2 * q], rp[2 * q + 1]);
    int base = t * 256 + c0 * 2, sw = (t & 7) << 4;
    *(uint4*)((char*)sm.hb + ((base) ^ sw))      = make_uint4(u[0], u[1], u[2], u[3]);
    *(uint4*)((char*)sm.hb + ((base + 16) ^ sw)) = make_uint4(u[4], u[5], u[6], u[7]);
  }
  __syncthreads();

  // ---- out-proj MFMA + residual: h += attn @ ow^T + ob. wave: mt=wv ----
  {
    f32x4 acc[3];
    #pragma unroll
    for (int j = 0; j < 3; ++j) acc[j] = (f32x4){0.f, 0.f, 0.f, 0.f};
    #pragma unroll
    for (int ks = 0; ks < 4; ++ks) {
      bf16x8 Af = *(const bf16x8*)(wp_ow + (size_t)((wv * 4 + ks) * 64 + ln) * 8);
      #pragma unroll
      for (int j = 0; j < 3; ++j) {
        int row = j * 16 + lr;
        bf16x8 Bf = *(const bf16x8*)((const char*)sm.hb +
                     ((row * 256 + ks * 64 + lg * 16) ^ ((row & 7) << 4)));
        acc[j] = MFMA16(Af, Bf, acc[j]);
      }
    }
    int hh0 = wv * 16 + lg * 4;
    float4 bias = *(const float4*)(ob + hh0);
    #pragma unroll
    for (int j = 0; j < 3; ++j) {
      int t = j * 16 + lr;
      float4 cur = *(const float4*)&sm.h[t][hh0];
      cur.x += acc[j].x + bias.x; cur.y += acc[j].y + bias.y;
      cur.z += acc[j].z + bias.z; cur.w += acc[j].w + bias.w;
      *(float4*)&sm.h[t][hh0] = cur;
    }
  }
  __syncthreads();

  // ---- LN1 ----
  {
    for (int t = wv; t < T_; t += 8) {
      float v0 = sm.h[t][ln], v1 = sm.h[t][ln + 64];
      float s = v0 + v1;
      #pragma unroll
      for (int off = 32; off; off >>= 1) s += __shfl_xor(s, off, 64);
      float mean = s * (1.f / H_);
      float d0 = v0 - mean, d1 = v1 - mean;
      float q = d0 * d0 + d1 * d1;
      #pragma unroll
      for (int off = 32; off; off >>= 1) q += __shfl_xor(q, off, 64);
      float rstd = rsqrtf(q * (1.f / H_) + 1e-5f);
      sm.h[t][ln]      = d0 * rstd * l1g[ln]      + l1b[ln];
      sm.h[t][ln + 64] = d1 * rstd * l1g[ln + 64] + l1b[ln + 64];
    }
  }
  __syncthreads();

  // ---- conv h -> hb ----
  if (tid < 384) {
    int t = tid >> 3, c0 = (tid & 7) * 16;
    const float* rp = &sm.h[t][c0];
    unsigned int u[8];
    #pragma unroll
    for (int q = 0; q < 8; ++q) u[q] = pk2(rp[2 * q], rp[2 * q + 1]);
    int base = t * 256 + c0 * 2, sw = (t & 7) << 4;
    *(uint4*)((char*)sm.hb + ((base) ^ sw))      = make_uint4(u[0], u[1], u[2], u[3]);
    *(uint4*)((char*)sm.hb + ((base + 16) ^ sw)) = make_uint4(u[4], u[5], u[6], u[7]);
  }
  __syncthreads();

  // ---- FFN1 MFMA: gb = gelu(h @ w1^T + b1) bf16. wave: mt 2w,2w+1 ----
  {
    f32x4 acc[2][3];
    #pragma unroll
    for (int i = 0; i < 2; ++i)
      #pragma unroll
      for (int j = 0; j < 3; ++j) acc[i][j] = (f32x4){0.f, 0.f, 0.f, 0.f};
    #pragma unroll
    for (int ks = 0; ks < 4; ++ks) {
      bf16x8 Af[2], Bf[3];
      #pragma unroll
      for (int i = 0; i < 2; ++i)
        Af[i] = *(const bf16x8*)(wp_w1 + (size_t)(((wv * 2 + i) * 4 + ks) * 64 + ln) * 8);
      #pragma unroll
      for (int j = 0; j < 3; ++j) {
        int row = j * 16 + lr;
        Bf[j] = *(const bf16x8*)((const char*)sm.hb +
                 ((row * 256 + ks * 64 + lg * 16) ^ ((row & 7) << 4)));
      }
      #pragma unroll
      for (int i = 0; i < 2; ++i)
        #pragma unroll
        for (int j = 0; j < 3; ++j) acc[i][j] = MFMA16(Af[i], Bf[j], acc[i][j]);
    }
    #pragma unroll
    for (int i = 0; i < 2; ++i) {
      int hh0 = (wv * 2 + i) * 16 + lg * 4;       // 0..255
      float4 bias = *(const float4*)(b1 + hh0);
      #pragma unroll
      for (int j = 0; j < 3; ++j) {
        int t = j * 16 + lr;
        float g0 = acc[i][j].x + bias.x, g1 = acc[i][j].y + bias.y;
        float g2 = acc[i][j].z + bias.z, g3 = acc[i][j].w + bias.w;
        g0 = 0.5f * g0 * (1.f + erff(g0 * 0.70710678118f));
        g1 = 0.5f * g1 * (1.f + erff(g1 * 0.70710678118f));
        g2 = 0.5f * g2 * (1.f + erff(g2 * 0.70710678118f));
        g3 = 0.5f * g3 * (1.f + erff(g3 * 0.70710678118f));
        int off = (t * 512 + hh0 * 2) ^ ((t & 7) << 4);
        *(uint2*)((char*)&sm.u.gb[0][0] + off) = make_uint2(pk2(g0, g1), pk2(g2, g3));
      }
    }
  }
  __syncthreads();

  // ---- FFN2 MFMA + residual: h += gb @ w2^T + b2. K=256. wave: mt=wv ----
  {
    f32x4 acc[3];
    #pragma unroll
    for (int j = 0; j < 3; ++j) acc[j] = (f32x4){0.f, 0.f, 0.f, 0.f};
    #pragma unroll
    for (int ks = 0; ks < 8; ++ks) {
      bf16x8 Af = *(const bf16x8*)(wp_w2 + (size_t)((wv * 8 + ks) * 64 + ln) * 8);
      #pragma unroll
      for (int j = 0; j < 3; ++j) {
        int row = j * 16 + lr;
        bf16x8 Bf = *(const bf16x8*)((const char*)&sm.u.gb[0][0] +
                     ((row * 512 + ks * 64 + lg * 16) ^ ((row & 7) << 4)));
        acc[j] = MFMA16(Af, Bf, acc[j]);
      }
    }
    int hh0 = wv * 16 + lg * 4;
    float4 bias = *(const float4*)(b2 + hh0);
    #pragma unroll
    for (int j = 0; j < 3; ++j) {
      int t = j * 16 + lr;
      float4 cur = *(const float4*)&sm.h[t][hh0];
      cur.x += acc[j].x + bias.x; cur.y += acc[j].y + bias.y;
      cur.z += acc[j].z + bias.z; cur.w += acc[j].w + bias.w;
      *(float4*)&sm.h[t][hh0] = cur;
    }
  }
  __syncthreads();

  // ---- LN2 ----
  {
    for (int t = wv; t < T_; t += 8) {
      float v0 = sm.h[t][ln], v1 = sm.h[t][ln + 64];
      float s = v0 + v1;
      #pragma unroll
      for (int off = 32; off; off >>= 1) s += __shfl_xor(s, off, 64);
      float mean = s * (1.f / H_);
      float d0 = v0 - mean, d1 = v1 - mean;
      float q = d0 * d0 + d1 * d1;
      #pragma unroll
      for (int off = 32; off; off >>= 1) q += __shfl_xor(q, off, 64);
      float rstd = rsqrtf(q * (1.f / H_) + 1e-5f);
      sm.h[t][ln]      = d0 * rstd * l2g[ln]      + l2b[ln];
      sm.h[t][ln + 64] = d1 * rstd * l2g[ln + 64] + l2b[ln + 64];
    }
  }
  __syncthreads();

  if (tid < H_) t_repr[(size_t)seq * H_ + tid] = sm.h[T_ - 1][tid];
}

// s_repr[n][hh] = relu(x_static[n] . stat_w[hh] + stat_b[hh])
__global__ __launch_bounds__(256)
void k_static(const float* __restrict__ xst, const float* __restrict__ sw,
              const float* __restrict__ sb, float* __restrict__ s_repr)
{
  int idx = blockIdx.x * 256 + threadIdx.x;   // 512*128
  int n = idx >> 7, hh = idx & 127;
  float s = sb[hh];
  #pragma unroll
  for (int c = 0; c < S_; ++c) s += xst[n * S_ + c] * sw[hh * S_ + c];
  s_repr[idx] = fmaxf(s, 0.f);
}

// gh[b,n,:] = node @ gat_w^T ; ga1/ga2 = gh . a1 / a2
__global__ __launch_bounds__(128)
void k_gatproj(const float* __restrict__ t_repr, const float* __restrict__ s_repr,
               const float* __restrict__ gat_w, const float* __restrict__ gat_a,
               float* __restrict__ gh, float* __restrict__ ga1, float* __restrict__ ga2)
{
  int bi = blockIdx.x;            // b*512+n
  int n = bi & (N_ - 1);
  int hh = threadIdx.x;
  const float* wr = gat_w + hh * 2 * H_;
  float s = dot128(t_repr + (size_t)bi * H_, wr) +
            dot128(s_repr + (size_t)n * H_, wr + H_);
  gh[(size_t)bi * H_ + hh] = s;
  float c1 = s * gat_a[hh];
  float c2 = s * gat_a[H_ + hh];
  #pragma unroll
  for (int off = 32; off; off >>= 1) {
    c1 += __shfl_xor(c1, off, 64);
    c2 += __shfl_xor(c2, off, 64);
  }
  __shared__ float r1[2], r2[2];
  int w = hh >> 6;
  if ((hh & 63) == 0) { r1[w] = c1; r2[w] = c2; }
  __syncthreads();
  if (hh == 0) { ga1[bi] = r1[0] + r1[1]; ga2[bi] = r2[0] + r2[1]; }
}

// per (b,i): e-row -> softmax -> alpha out; g_repr; fused; heads
__global__ __launch_bounds__(256)
void k_gat(const int* __restrict__ adj, const float* __restrict__ gh,
           const float* __restrict__ ga1, const float* __restrict__ ga2,
           const float* __restrict__ t_repr, const float* __restrict__ s_repr,
           const float* __restrict__ fw, const float* __restrict__ fb,
           const float* __restrict__ regw, const float* __restrict__ regb,
           const float* __restrict__ riskw, const float* __restrict__ riskb,
           const float* __restrict__ warnw, const float* __restrict__ warnb,
           float* __restrict__ out_alpha, float* __restrict__ out_reg,
           float* __restrict__ out_risk, float* __restrict__ out_warn)
{
  const int row = blockIdx.x;     // b*512 + i
  const int bb = row >> 9, i = row & (N_ - 1);
  const int tid = threadIdx.x;
  __shared__ float ev[N_];
  alignas(16) __shared__ float gr[H_];
  alignas(16) __shared__ float fus[H_];
  __shared__ float red[4];

  const float g1 = ga1[row];
  const float* g2 = ga2 + (size_t)bb * N_;
  float lmax = -1e30f;
  for (int j = tid; j < N_; j += 256) {
    float e = g1 + g2[j];
    e = e > 0.f ? e : 0.2f * e;               // leaky_relu(0.2)
    if (adj[i * N_ + j] == 0) e = -1e30f;     // mask
    ev[j] = e; lmax = fmaxf(lmax, e);
  }
  #pragma unroll
  for (int off = 32; off; off >>= 1) lmax = fmaxf(lmax, __shfl_xor(lmax, off, 64));
  if ((tid & 63) == 0) red[tid >> 6] = lmax;
  __syncthreads();
  const float m = fmaxf(fmaxf(red[0], red[1]), fmaxf(red[2], red[3]));
  float lsum = 0.f;
  for (int j = tid; j < N_; j += 256) {
    float p = __expf(ev[j] - m);
    ev[j] = p; lsum += p;
  }
  #pragma unroll
  for (int off = 32; off; off >>= 1) lsum += __shfl_xor(lsum, off, 64);
  __syncthreads();                             // all have read red (max)
  if ((tid & 63) == 0) red[tid >> 6] = lsum;
  __syncthreads();
  const float inv = 1.f / (red[0] + red[1] + red[2] + red[3]);
  for (int j = tid; j < N_; j += 256) {
    float a = ev[j] * inv;
    ev[j] = a;
    out_alpha[(size_t)row * N_ + j] = a;
  }
  __syncthreads();

  if (tid < H_) {                              // g_repr[hh] = sum_j alpha_j * gh[b,j,hh]
    float acc = 0.f;
    const float* ghb = gh + (size_t)bb * N_ * H_ + tid;
    for (int j = 0; j < N_; ++j) acc += ev[j] * ghb[(size_t)j * H_];
    gr[tid] = acc;
  }
  __syncthreads();
  if (tid < H_) {                              // fused = relu([t_repr, s_repr, g_repr] @ fuse_w^T + b)
    const float* wr = fw + tid * 3 * H_;
    float s = fb[tid] +
              dot128(t_repr + (size_t)row * H_, wr) +
              dot128(s_repr + (size_t)i * H_, wr + H_) +
              dot128(gr, wr + 2 * H_);
    fus[tid] = fmaxf(s, 0.f);
  }
  __syncthreads();
  if (tid < 30) {                              // heads: 6 reg, 18 risk, 6 warn
    const float *wp, *bp; float* op; int o;
    if (tid < 6)       { o = tid;      wp = regw  + o * H_; bp = regb  + o; op = out_reg  + (size_t)row * 6  + o; }
    else if (tid < 24) { o = tid - 6;  wp = riskw + o * H_; bp = riskb + o; op = out_risk + (size_t)row * 18 + o; }
    else               { o = tid - 24; wp = warnw + o * H_; bp = warnb + o; op = out_warn + (size_t)row * 6  + o; }
    float s = *bp + dot128(fus, wp);
    *op = s;
  }
}

extern "C" void kernel_launch(void* const* d_in, const int* in_sizes, int n_in,
                              void* d_out, int out_size, void* d_ws, size_t ws_size,
                              hipStream_t stream)
{
  const float* x    = (const float*)d_in[0];
  const float* xst  = (const float*)d_in[1];
  const int*   adj  = (const int*)d_in[2];
  const float* pw   = (const float*)d_in[3];
  const float* pb   = (const float*)d_in[4];
  const float* inw  = (const float*)d_in[5];
  const float* inb  = (const float*)d_in[6];
  const float* ow   = (const float*)d_in[7];
  const float* ob   = (const float*)d_in[8];
  const float* l1g  = (const float*)d_in[9];
  const float* l1b  = (const float*)d_in[10];
  const float* w1   = (const float*)d_in[11];
  const float* b1   = (const float*)d_in[12];
  const float* w2   = (const float*)d_in[13];
  const float* b2   = (const float*)d_in[14];
  const float* l2g  = (const float*)d_in[15];
  const float* l2b  = (const float*)d_in[16];
  const float* stw  = (const float*)d_in[17];
  const float* stb  = (const float*)d_in[18];
  const float* gatw = (const float*)d_in[19];
  const float* gata = (const float*)d_in[20];
  const float* fw   = (const float*)d_in[21];
  const float* fb   = (const float*)d_in[22];
  const float* regw = (const float*)d_in[23];
  const float* regb = (const float*)d_in[24];
  const float* rkw  = (const float*)d_in[25];
  const float* rkb  = (const float*)d_in[26];
  const float* wnw  = (const float*)d_in[27];
  const float* wnb  = (const float*)d_in[28];

  float* out       = (float*)d_out;
  float* out_reg   = out;                 // 24576
  float* out_risk  = out + 24576;         // 73728
  float* out_warn  = out + 98304;         // 24576
  float* out_tatt  = out + 122880;        // 9437184
  float* out_alpha = out + 9560064;       // 2097152

  float* ws     = (float*)d_ws;           // f32 scratch (4,489,216 B total, proven)
  float* t_repr = ws;                     // 4096*128
  float* s_repr = ws + 524288;            // 512*128
  float* gh     = ws + 589824;            // 4096*128  (wpk aliases the front of this)
  float* ga1    = ws + 1114112;           // 4096
  float* ga2    = ws + 1118208;           // 4096
  // wpk lifetime: k_prep(write) -> k_seq(read); gh is written only afterwards
  // by k_gatproj, so aliasing is safe on the in-order stream.
  ushort_t* wpk = (ushort_t*)gh;          // 131072 bf16 = 256KB < 2MB gh region

  k_prep<<<dim3(512), dim3(256), 0, stream>>>(inw, ow, w1, w2, wpk);
  k_seq<<<dim3(B_ * N_), dim3(512), 0, stream>>>(
      x, pw, pb, inb, ob, l1g, l1b, b1, b2, l2g, l2b, wpk,
      out_tatt, t_repr);
  k_static<<<dim3(256), dim3(256), 0, stream>>>(xst, stw, stb, s_repr);
  k_gatproj<<<dim3(B_ * N_), dim3(128), 0, stream>>>(
      t_repr, s_repr, gatw, gata, gh, ga1, ga2);
  k_gat<<<dim3(B_ * N_), dim3(256), 0, stream>>>(
      adj, gh, ga1, ga2, t_repr, s_repr, fw, fb,
      regw, regb, rkw, rkb, wnw, wnb,
      out_alpha, out_reg, out_risk, out_warn);
}